// Round 13
// baseline (76.705 us; speedup 1.0000x reference)
//
#include <hip/hip_runtime.h>
#include <hip/hip_bf16.h>

// MMD loss: source/target 4096x256 fp32, output scalar fp32. N=8192, D=256.
// R13: BARRIER-FREE wave-private k_mmd. R3-R12 showed the 4-wave barrier-locked
// chunk loop is stuck at 43-47us regardless of buffering/grid/persistence
// (m233: the 2-phase barrier structure is ~72% overhead at low MFMA density).
// Fix: each wave owns a private 16KB LDS slice (2 bufs x (A 4KB + B 4KB)),
// stages its own 64-row halves (8 gl_lds/chunk), waits its own counted
// vmcnt(8), reads + MFMAs. ZERO barriers in k_mmd; waves drift so MFMA /
// VALU-epilogue / loads from different waves co-schedule (m114).
//
// ws layout (bytes):
//   0      : double slots[2048]         -> 16384
//   16384  : double neg_gamma2          -> 16392
//   16392  : double sqpart[128]         -> 17416
//   17416  : float  cspart[128*256]     -> 148488
//   148488 : float  sq[8192]            -> 181256
//   181264 : bf16   G[8192*256]         -> 4375568
#define WS_SLOT_OFF   0
#define WS_NEGG_OFF   16384
#define WS_SQPART_OFF 16392
#define WS_CSPART_OFF 17416
#define WS_SQ_OFF     148488
#define WS_G_OFF      181264

#define NROW 8192
#define HALF 4096
#define DIM  256
#define TILE 128
#define NB   64                     // 8192/128 row-tiles
#define NPAIR (NB * (NB + 1) / 2)   // 2080 upper-tri tile pairs
#define GRID_M 512                  // k_mmd blocks (all co-resident, 2/CU)
#define KC   32                     // k-chunk (64 B/row)
#define NC   (DIM / KC)             // 8 chunks per pair
#define PREPB 128                   // k_prep blocks (64 rows each)
// per-wave LDS (ushort idx): 2 bufs * 4096 (A 2048 + B 2048) = 8192 -> 16 KB

typedef short  short8 __attribute__((ext_vector_type(8)));
typedef float  f32x4  __attribute__((ext_vector_type(4)));
typedef float  f32x2  __attribute__((ext_vector_type(2)));
typedef unsigned short us4 __attribute__((ext_vector_type(4)));

static __device__ __forceinline__ unsigned short f2bfbits(float f) {
    __hip_bfloat16 h = __float2bfloat16(f);   // RNE
    return *reinterpret_cast<unsigned short*>(&h);
}
static __device__ __forceinline__ float bfbits2f(unsigned short u) {
    return __uint_as_float(((unsigned int)u) << 16);
}
static __device__ __forceinline__ void gl_lds16(const void* g, void* l) {
    __builtin_amdgcn_global_load_lds(
        (const __attribute__((address_space(1))) void*)g,
        (__attribute__((address_space(3))) void*)l, 16, 0, 0);
}

// ---------- kernel A: cvt + row-sq + per-block colsum/sqsum partials ----------
__global__ __launch_bounds__(256) void k_prep(const float* __restrict__ src,
                                              const float* __restrict__ tgt,
                                              unsigned short* __restrict__ G,
                                              float* __restrict__ sq,
                                              float* __restrict__ cspart,
                                              double* __restrict__ sqpart) {
    __shared__ float cs_lds[4 * 256];
    __shared__ double sq_lds[4];

    int t = threadIdx.x, wid = t >> 6, lane = t & 63;
    int r0 = blockIdx.x * 64;
    int c4 = lane * 4;

    float cs0 = 0.f, cs1 = 0.f, cs2 = 0.f, cs3 = 0.f;
    double wsq = 0.0;
    for (int i = 0; i < 16; ++i) {
        int row = r0 + wid + i * 4;
        const float* base = (row < HALF) ? (src + (size_t)row * DIM)
                                         : (tgt + (size_t)(row - HALF) * DIM);
        float4 v = *(const float4*)(base + c4);
        unsigned short u0 = f2bfbits(v.x), u1 = f2bfbits(v.y),
                       u2 = f2bfbits(v.z), u3 = f2bfbits(v.w);
        us4 uu = {u0, u1, u2, u3};
        *(us4*)(G + (size_t)row * DIM + c4) = uu;   // linear, coalesced
        float r0f = bfbits2f(u0), r1f = bfbits2f(u1),
              r2f = bfbits2f(u2), r3f = bfbits2f(u3);
        cs0 += r0f; cs1 += r1f; cs2 += r2f; cs3 += r3f;
        float s = r0f * r0f + r1f * r1f + r2f * r2f + r3f * r3f;
        #pragma unroll
        for (int off = 32; off; off >>= 1) s += __shfl_down(s, off);
        if (lane == 0) { sq[row] = s; wsq += (double)s; }
    }
    cs_lds[wid * 256 + c4 + 0] = cs0;
    cs_lds[wid * 256 + c4 + 1] = cs1;
    cs_lds[wid * 256 + c4 + 2] = cs2;
    cs_lds[wid * 256 + c4 + 3] = cs3;
    if (lane == 0) sq_lds[wid] = wsq;
    __syncthreads();
    float s = cs_lds[t] + cs_lds[256 + t] + cs_lds[512 + t] + cs_lds[768 + t];
    cspart[blockIdx.x * 256 + t] = s;
    if (t == 0)
        sqpart[blockIdx.x] = sq_lds[0] + sq_lds[1] + sq_lds[2] + sq_lds[3];
}

// ---------- kernel B: bandwidth -> neg_gamma2 = -log2(e)/(16*bw) ----------
__global__ __launch_bounds__(256) void k_bw(const float* __restrict__ cspart,
                                            const double* __restrict__ sqpart,
                                            double* __restrict__ negg) {
    __shared__ double red[256];
    __shared__ double red2[256];
    int t = threadIdx.x;
    double c = 0.0;
    for (int b = 0; b < PREPB; ++b) c += (double)cspart[b * 256 + t];
    double s = (t < PREPB) ? sqpart[t] : 0.0;
    red[t]  = s;
    red2[t] = c * c;
    __syncthreads();
    for (int off = 128; off; off >>= 1) {
        if (t < off) { red[t] += red[t + off]; red2[t] += red2[t + off]; }
        __syncthreads();
    }
    if (t == 0) {
        const double N = (double)NROW;
        double sum_l2 = 2.0 * N * red[0] - 2.0 * red2[0];
        double bw = sum_l2 / (N * N - N);
        bw = bw / 4.0;  // KERNEL_MUL ** (KERNEL_NUM//2) = 2^2
        negg[0] = -1.4426950408889634 / (16.0 * bw);  // exp2 scaling
    }
}

// ---------- kernel D: barrier-free wave-private MFMA pass ----------
// Per-wave LDS slice: [buf][A|B][64 rows x 32 ushorts]. Row r, physical slot
// p holds logical p ^ ((r>>1)&3) (2-way-max banks on b128 reads; linear
// gl_lds dest with pre-swizzled source — the proven R4 involution).
__global__ __launch_bounds__(256, 2) void k_mmd(const unsigned short* __restrict__ G,
                                                const float* __restrict__ sq,
                                                const double* __restrict__ negg,
                                                double* __restrict__ slots) {
    __shared__ unsigned short lds[4 * 8192];   // 64 KB, 16 KB per wave

    int bid = blockIdx.x;
    int swz = (bid & 7) * (GRID_M / 8) + (bid >> 3);   // XCD-chunked, bijective

    int t = threadIdx.x, wid = t >> 6, lane = t & 63;
    int wr = wid >> 1, wc = wid & 1;
    int rl = lane & 15, klane = lane >> 4;
    int ldsW = wid * 8192;

    // staging geometry (loop-invariant): lane -> local row lane>>2 (+16i),
    // physical slot lane&3; source slot = (lane&3) ^ ((lane>>3)&3) (i-indep)
    int slog = (lane & 3) ^ ((lane >> 3) & 3);
    size_t gsA = (size_t)(wr * 64 + (lane >> 2)) * DIM + slog * 8;
    size_t gsB = (size_t)(wc * 64 + (lane >> 2)) * DIM + slog * 8;

    // fragment-read offsets within wave slice (i-indep swizzle kswz)
    int kswz = (klane ^ ((rl >> 1) & 3)) * 8;
    int aoff[4], boff[4];
    #pragma unroll
    for (int f = 0; f < 4; ++f) {
        aoff[f] = f * 512 + rl * 32 + kswz;
        boff[f] = 2048 + f * 512 + rl * 32 + kswz;
    }

    float ng2 = (float)negg[0];               // negative
    float m2g = -2.0f * ng2;                  // positive
    f32x2 m2g2 = {m2g, m2g};
    int rgrp = lane >> 4;

    double bsum = 0.0;

    #define STAGE(Ab_, Bb_, kcc, buf)                                         \
        do {                                                                  \
            _Pragma("unroll")                                                 \
            for (int i_ = 0; i_ < 4; ++i_) {                                  \
                gl_lds16((Ab_) + gsA + (size_t)i_ * 16 * DIM + (kcc) * KC,    \
                         &lds[ldsW + (buf) * 4096 + i_ * 512]);               \
                gl_lds16((Bb_) + gsB + (size_t)i_ * 16 * DIM + (kcc) * KC,    \
                         &lds[ldsW + (buf) * 4096 + 2048 + i_ * 512]);        \
            }                                                                 \
        } while (0)

    // first pair decode
    int p = swz;
    int bi = 0, rem = p;
    while (rem >= NB - bi) { rem -= NB - bi; ++bi; }
    int bj = bi + rem;
    const unsigned short* Acur = G + (size_t)bi * TILE * DIM;
    const unsigned short* Bcur = G + (size_t)bj * TILE * DIM;

    // prologue: chunks 0,1 of first pair (16 loads in flight)
    STAGE(Acur, Bcur, 0, 0);
    STAGE(Acur, Bcur, 1, 1);

    while (true) {
        // decode next pair while loads fly
        int pn = p + GRID_M;
        bool last = (pn >= NPAIR);
        const unsigned short* Anxt = Acur;
        const unsigned short* Bnxt = Bcur;
        int bin = bi, bjn = bj;
        if (!last) {
            int b2 = 0, r2 = pn;
            while (r2 >= NB - b2) { r2 -= NB - b2; ++b2; }
            bin = b2; bjn = b2 + r2;
            Anxt = G + (size_t)bin * TILE * DIM;
            Bnxt = G + (size_t)bjn * TILE * DIM;
        }

        const f32x4 zero4 = {0.f, 0.f, 0.f, 0.f};
        f32x4 acc[4][4];
        #pragma unroll
        for (int i = 0; i < 4; ++i)
            #pragma unroll
            for (int j = 0; j < 4; ++j) acc[i][j] = zero4;

        #pragma unroll
        for (int kc = 0; kc < NC; ++kc) {
            // wait for THIS wave's chunk kc (8 oldest); keep kc+1's 8 in flight
            if (kc == NC - 1 && last) {
                asm volatile("s_waitcnt vmcnt(0)" ::: "memory");
            } else {
                asm volatile("s_waitcnt vmcnt(8)" ::: "memory");
            }
            __builtin_amdgcn_sched_barrier(0);

            const unsigned short* base = &lds[ldsW + (kc & 1) * 4096];
            short8 af[4], bfv[4];
            #pragma unroll
            for (int f = 0; f < 4; ++f) {
                af[f]  = *(const short8*)&base[aoff[f]];
                bfv[f] = *(const short8*)&base[boff[f]];
            }
            #pragma unroll
            for (int i = 0; i < 4; ++i)
                #pragma unroll
                for (int j = 0; j < 4; ++j)
                    acc[i][j] = __builtin_amdgcn_mfma_f32_16x16x32_bf16(
                        af[i], bfv[j], acc[i][j], 0, 0, 0);

            // stage chunk kc+2 into buf (kc&1) AFTER its reads are consumed
            // (DMA write lands >=200cyc post-issue; reads completed above)
            __builtin_amdgcn_sched_barrier(0);
            if (kc < NC - 2)   { STAGE(Acur, Bcur, kc + 2, kc & 1); }
            else if (!last)    { STAGE(Anxt, Bnxt, kc - 6, kc & 1); }
        }

        // ---- epilogue (overlaps other waves' K-loops; no sync) ----
        // C/D layout (m89): col = lane&15, row = (lane>>4)*4 + reg
        int gi0 = bi * TILE + wr * 64;
        int gj0 = bj * TILE + wc * 64;

        float sqb4[4];
        #pragma unroll
        for (int j = 0; j < 4; ++j) sqb4[j] = sq[gj0 + j * 16 + rl] * ng2;

        f32x2 tsv = {0.f, 0.f};
        #pragma unroll
        for (int i = 0; i < 4; ++i) {
            int base2 = gi0 + i * 16 + rgrp * 4;
            f32x2 sa01 = {sq[base2 + 0] * ng2, sq[base2 + 1] * ng2};
            f32x2 sa23 = {sq[base2 + 2] * ng2, sq[base2 + 3] * ng2};
            #pragma unroll
            for (int j = 0; j < 4; ++j) {
                f32x2 sb = {sqb4[j], sqb4[j]};
                f32x2 x01 = {acc[i][j][0], acc[i][j][1]};
                f32x2 x23 = {acc[i][j][2], acc[i][j][3]};
                x01 = x01 * m2g2 + (sa01 + sb);   // v_pk_fma + v_pk_add
                x23 = x23 * m2g2 + (sa23 + sb);
                f32x2 e01, e23;
                e01.x = exp2f(x01.x); e01.y = exp2f(x01.y);
                e23.x = exp2f(x23.x); e23.y = exp2f(x23.y);
                f32x2 p01 = e01 * e01, q01 = p01 * p01,
                      r01 = q01 * q01, s01 = r01 * r01;
                f32x2 p23 = e23 * e23, q23 = p23 * p23,
                      r23 = q23 * q23, s23 = r23 * r23;
                tsv += ((e01 + p01) + (q01 + r01)) + s01;
                tsv += ((e23 + p23) + (q23 + r23)) + s23;
            }
        }
        float tsum = tsv.x + tsv.y;

        float w = ((bi < 32) == (bj < 32)) ? 1.f : -1.f;
        if (bi != bj) w *= 2.f;   // off-diagonal tiles count twice (symmetry)
        bsum += (double)(tsum * w);

        if (last) break;
        p = pn; bi = bin; bj = bjn; Acur = Anxt; Bcur = Bnxt;
    }
    #undef STAGE

    // per-wave reduce + store (no block sync anywhere)
    #pragma unroll
    for (int off = 32; off; off >>= 1) bsum += __shfl_down(bsum, off);
    if (lane == 0) slots[bid * 4 + wid] = bsum;
}

// ---------- kernel E: finalize (reduce 2048 per-wave slots) ----------
__global__ __launch_bounds__(256) void k_final(const double* __restrict__ slots,
                                               float* __restrict__ out) {
    __shared__ double red[256];
    int t = threadIdx.x;
    double s = 0.0;
    #pragma unroll
    for (int i = 0; i < 8; ++i) s += slots[t + i * 256];
    red[t] = s;
    __syncthreads();
    for (int off = 128; off; off >>= 1) {
        if (t < off) red[t] += red[t + off];
        __syncthreads();
    }
    if (t == 0)
        out[0] = (float)(red[0] / ((double)HALF * (double)HALF));
}

extern "C" void kernel_launch(void* const* d_in, const int* in_sizes, int n_in,
                              void* d_out, int out_size, void* d_ws, size_t ws_size,
                              hipStream_t stream) {
    const float* src = (const float*)d_in[0];
    const float* tgt = (const float*)d_in[1];
    float* out = (float*)d_out;

    double* slots     = (double*)((char*)d_ws + WS_SLOT_OFF);
    double* negg      = (double*)((char*)d_ws + WS_NEGG_OFF);
    double* sqpart    = (double*)((char*)d_ws + WS_SQPART_OFF);
    float*  cspart    = (float*)((char*)d_ws + WS_CSPART_OFF);
    float*  sq        = (float*)((char*)d_ws + WS_SQ_OFF);
    unsigned short* G = (unsigned short*)((char*)d_ws + WS_G_OFF);

    k_prep<<<PREPB, 256, 0, stream>>>(src, tgt, G, sq, cspart, sqpart);
    k_bw<<<1, 256, 0, stream>>>(cspart, sqpart, negg);
    k_mmd<<<GRID_M, 256, 0, stream>>>(G, sq, negg, slots);
    k_final<<<1, 256, 0, stream>>>(slots, out);
}

// Round 14
// 65.652 us; speedup vs baseline: 1.1684x; 1.1684x over previous
//
#include <hip/hip_runtime.h>
#include <hip/hip_bf16.h>

// MMD loss: source/target 4096x256 fp32, output scalar fp32. N=8192, D=256.
// R14 = R10's k_mmd (double-buffer 32KB, vmcnt(0)/chunk — measured ~15us once
// the 42.9us fillBuffer was subtracted) + R11's no-memset plumbing.
// Trajectory law: dur x resident-waves ~ const (latency-bound) -> 32KB LDS
// (4 blocks/CU) beats 48KB triple-buffer (3 blocks/CU); prefetch depth is
// irrelevant. No memset, no atomics, no fences anywhere.
//
// ws layout (bytes):
//   0      : double slots[2080]          -> 16640
//   16640  : double neg_gamma2           -> 16648
//   16648  : double sqpart[128]          -> 17672
//   17672  : float  cspart[128*256]      -> 148744
//   148744 : float  sq[8192]             -> 181512
//   181520 : bf16   G[8192*256]          -> 4375824
#define WS_SLOT_OFF   0
#define WS_NEGG_OFF   16640
#define WS_SQPART_OFF 16648
#define WS_CSPART_OFF 17672
#define WS_SQ_OFF     148744
#define WS_G_OFF      181520

#define NROW 8192
#define HALF 4096
#define DIM  256
#define TILE 128
#define NB   64                     // 8192/128 row-tiles
#define NBLK (NB * (NB + 1) / 2)    // 2080 upper-tri tile pairs
#define KC   32                     // k-chunk (64 B/row)
#define NC   (DIM / KC)             // 8 chunks
#define BUFE (TILE * KC)            // 4096 ushorts / buffer (8 KB)
#define PREPB 128                   // k_prep blocks (64 rows each)

typedef short  short8 __attribute__((ext_vector_type(8)));
typedef float  f32x4  __attribute__((ext_vector_type(4)));
typedef float  f32x2  __attribute__((ext_vector_type(2)));
typedef unsigned short us4 __attribute__((ext_vector_type(4)));

static __device__ __forceinline__ unsigned short f2bfbits(float f) {
    __hip_bfloat16 h = __float2bfloat16(f);   // RNE
    return *reinterpret_cast<unsigned short*>(&h);
}
static __device__ __forceinline__ float bfbits2f(unsigned short u) {
    return __uint_as_float(((unsigned int)u) << 16);
}
static __device__ __forceinline__ void gl_lds16(const void* g, void* l) {
    __builtin_amdgcn_global_load_lds(
        (const __attribute__((address_space(1))) void*)g,
        (__attribute__((address_space(3))) void*)l, 16, 0, 0);
}

// ---------- kernel A: cvt + row-sq + per-block colsum/sqsum partials ----------
// 128 blocks x 256 threads; block handles 64 rows; wave w rows r0+w+4i, i<16.
__global__ __launch_bounds__(256) void k_prep(const float* __restrict__ src,
                                              const float* __restrict__ tgt,
                                              unsigned short* __restrict__ G,
                                              float* __restrict__ sq,
                                              float* __restrict__ cspart,
                                              double* __restrict__ sqpart) {
    __shared__ float cs_lds[4 * 256];
    __shared__ double sq_lds[4];

    int t = threadIdx.x, wid = t >> 6, lane = t & 63;
    int r0 = blockIdx.x * 64;
    int c4 = lane * 4;

    float cs0 = 0.f, cs1 = 0.f, cs2 = 0.f, cs3 = 0.f;
    double wsq = 0.0;
    for (int i = 0; i < 16; ++i) {
        int row = r0 + wid + i * 4;
        const float* base = (row < HALF) ? (src + (size_t)row * DIM)
                                         : (tgt + (size_t)(row - HALF) * DIM);
        float4 v = *(const float4*)(base + c4);
        unsigned short u0 = f2bfbits(v.x), u1 = f2bfbits(v.y),
                       u2 = f2bfbits(v.z), u3 = f2bfbits(v.w);
        us4 uu = {u0, u1, u2, u3};
        *(us4*)(G + (size_t)row * DIM + c4) = uu;   // linear, coalesced
        float r0f = bfbits2f(u0), r1f = bfbits2f(u1),
              r2f = bfbits2f(u2), r3f = bfbits2f(u3);
        cs0 += r0f; cs1 += r1f; cs2 += r2f; cs3 += r3f;
        float s = r0f * r0f + r1f * r1f + r2f * r2f + r3f * r3f;
        #pragma unroll
        for (int off = 32; off; off >>= 1) s += __shfl_down(s, off);
        if (lane == 0) { sq[row] = s; wsq += (double)s; }
    }
    cs_lds[wid * 256 + c4 + 0] = cs0;
    cs_lds[wid * 256 + c4 + 1] = cs1;
    cs_lds[wid * 256 + c4 + 2] = cs2;
    cs_lds[wid * 256 + c4 + 3] = cs3;
    if (lane == 0) sq_lds[wid] = wsq;
    __syncthreads();
    float s = cs_lds[t] + cs_lds[256 + t] + cs_lds[512 + t] + cs_lds[768 + t];
    cspart[blockIdx.x * 256 + t] = s;
    if (t == 0)
        sqpart[blockIdx.x] = sq_lds[0] + sq_lds[1] + sq_lds[2] + sq_lds[3];
}

// ---------- kernel B: bandwidth -> neg_gamma2 = -log2(e)/(16*bw) ----------
__global__ __launch_bounds__(256) void k_bw(const float* __restrict__ cspart,
                                            const double* __restrict__ sqpart,
                                            double* __restrict__ negg) {
    __shared__ double red[256];
    __shared__ double red2[256];
    int t = threadIdx.x;
    double c = 0.0;
    for (int b = 0; b < PREPB; ++b) c += (double)cspart[b * 256 + t];
    double s = (t < PREPB) ? sqpart[t] : 0.0;
    red[t]  = s;
    red2[t] = c * c;
    __syncthreads();
    for (int off = 128; off; off >>= 1) {
        if (t < off) { red[t] += red[t + off]; red2[t] += red2[t + off]; }
        __syncthreads();
    }
    if (t == 0) {
        const double N = (double)NROW;
        double sum_l2 = 2.0 * N * red[0] - 2.0 * red2[0];
        double bw = sum_l2 / (N * N - N);
        bw = bw / 4.0;  // KERNEL_MUL ** (KERNEL_NUM//2) = 2^2
        negg[0] = -1.4426950408889634 / (16.0 * bw);  // exp2 scaling
    }
}

// ---------- kernel D: MFMA pairwise pass (R10's proven double-buffer loop) --
// LDS [row][k] bf16, KC=32 (4 slots of 16 B). Physical slot p at row r holds
// logical slot p ^ ((r>>1)&3): 2-way-max bank aliasing on b128 frag reads,
// linear global_load_lds dest (source pre-swizzled, involution).
__global__ __launch_bounds__(256, 3) void k_mmd(const unsigned short* __restrict__ G,
                                                const float* __restrict__ sq,
                                                const double* __restrict__ negg,
                                                double* __restrict__ slots) {
    __shared__ unsigned short As[2 * BUFE];   // 16 KB
    __shared__ unsigned short Bs[2 * BUFE];   // 16 KB
    __shared__ double wsum[4];

    // decode linear block id -> (bi, bj) with bi <= bj
    int bi = 0, rem = blockIdx.x;
    while (rem >= NB - bi) { rem -= NB - bi; ++bi; }
    int bj = bi + rem;

    int t = threadIdx.x, wid = t >> 6, lane = t & 63;
    int wr = wid >> 1, wc = wid & 1;
    int rl = lane & 15, klane = lane >> 4;

    const unsigned short* Abase = G + (size_t)bi * TILE * DIM;
    const unsigned short* Bbase = G + (size_t)bj * TILE * DIM;

    // staging: wave stages rows [wid*32, wid*32+32); load i covers 16 rows
    // (lane -> row +(lane>>2), physical slot lane&3)
    int lr0 = wid * 32 + (lane >> 2);
    int slog0 = (lane & 3) ^ ((lr0 >> 1) & 3);
    int lr1 = lr0 + 16;
    int slog1 = (lane & 3) ^ ((lr1 >> 1) & 3);
    size_t ga0 = (size_t)lr0 * DIM + slog0 * 8;
    size_t ga1 = (size_t)lr1 * DIM + slog1 * 8;
    int ld0 = (wid * 32) * KC;
    int ld1 = (wid * 32 + 16) * KC;

    // fragment-read offsets (loop-invariant)
    int aoff[4], boff[4];
    #pragma unroll
    for (int f = 0; f < 4; ++f) {
        int ra = wr * 64 + f * 16 + rl;
        aoff[f] = ra * KC + ((klane ^ ((ra >> 1) & 3)) * 8);
        int rb = wc * 64 + f * 16 + rl;
        boff[f] = rb * KC + ((klane ^ ((rb >> 1) & 3)) * 8);
    }

    const f32x4 zero4 = {0.f, 0.f, 0.f, 0.f};
    f32x4 acc[4][4];
    #pragma unroll
    for (int i = 0; i < 4; ++i)
        #pragma unroll
        for (int j = 0; j < 4; ++j) acc[i][j] = zero4;

    #define STAGE(kc, b)                                                     \
        do {                                                                 \
            gl_lds16(Abase + ga0 + (kc) * KC, &As[(b) * BUFE + ld0]);        \
            gl_lds16(Bbase + ga0 + (kc) * KC, &Bs[(b) * BUFE + ld0]);        \
            gl_lds16(Abase + ga1 + (kc) * KC, &As[(b) * BUFE + ld1]);        \
            gl_lds16(Bbase + ga1 + (kc) * KC, &Bs[(b) * BUFE + ld1]);        \
        } while (0)

    STAGE(0, 0);
    #pragma unroll
    for (int kc = 0; kc < NC; ++kc) {
        asm volatile("s_waitcnt vmcnt(0)" ::: "memory");  // my 4 loads of kc done
        __builtin_amdgcn_s_barrier();                      // everyone's done
        __builtin_amdgcn_sched_barrier(0);
        if (kc + 1 < NC) STAGE(kc + 1, (kc + 1) & 1);      // safe: buf consumed at kc-1

        const unsigned short* Ab = &As[(kc & 1) * BUFE];
        const unsigned short* Bb = &Bs[(kc & 1) * BUFE];
        short8 af[4], bfv[4];
        #pragma unroll
        for (int f = 0; f < 4; ++f) {
            af[f]  = *(const short8*)&Ab[aoff[f]];
            bfv[f] = *(const short8*)&Bb[boff[f]];
        }
        #pragma unroll
        for (int i = 0; i < 4; ++i)
            #pragma unroll
            for (int j = 0; j < 4; ++j)
                acc[i][j] = __builtin_amdgcn_mfma_f32_16x16x32_bf16(
                    af[i], bfv[j], acc[i][j], 0, 0, 0);
    }
    #undef STAGE

    // ---- epilogue: packed-f32 exp2-squaring chain (no clamp: off-diag
    // l2 > 0; diag |x| < 1e-7 -> output error ~1e-9) ----
    // C/D layout (m89): col = lane&15, row = (lane>>4)*4 + reg
    int gi0 = bi * TILE + wr * 64;
    int gj0 = bj * TILE + wc * 64;
    float ng2 = (float)negg[0];               // negative
    float m2g = -2.0f * ng2;                  // positive
    f32x2 m2g2 = {m2g, m2g};
    int rgrp = lane >> 4;

    float sqb4[4];
    #pragma unroll
    for (int j = 0; j < 4; ++j) sqb4[j] = sq[gj0 + j * 16 + rl] * ng2;

    f32x2 tsv = {0.f, 0.f};
    #pragma unroll
    for (int i = 0; i < 4; ++i) {
        int base = gi0 + i * 16 + rgrp * 4;
        f32x2 sa01 = {sq[base + 0] * ng2, sq[base + 1] * ng2};
        f32x2 sa23 = {sq[base + 2] * ng2, sq[base + 3] * ng2};
        #pragma unroll
        for (int j = 0; j < 4; ++j) {
            f32x2 sb = {sqb4[j], sqb4[j]};
            f32x2 x01 = {acc[i][j][0], acc[i][j][1]};
            f32x2 x23 = {acc[i][j][2], acc[i][j][3]};
            x01 = x01 * m2g2 + (sa01 + sb);   // v_pk_fma + v_pk_add
            x23 = x23 * m2g2 + (sa23 + sb);
            f32x2 e01, e23;
            e01.x = exp2f(x01.x); e01.y = exp2f(x01.y);
            e23.x = exp2f(x23.x); e23.y = exp2f(x23.y);
            f32x2 p01 = e01 * e01, q01 = p01 * p01,
                  r01 = q01 * q01, s01 = r01 * r01;
            f32x2 p23 = e23 * e23, q23 = p23 * p23,
                  r23 = q23 * q23, s23 = r23 * r23;
            tsv += ((e01 + p01) + (q01 + r01)) + s01;
            tsv += ((e23 + p23) + (q23 + r23)) + s23;
        }
    }
    float tsum = tsv.x + tsv.y;

    float w = ((bi < 32) == (bj < 32)) ? 1.f : -1.f;
    if (bi != bj) w *= 2.f;   // off-diagonal tiles count twice (symmetry)
    double dsum = (double)tsum * (double)w;

    #pragma unroll
    for (int off = 32; off; off >>= 1) dsum += __shfl_down(dsum, off);
    if (lane == 0) wsum[wid] = dsum;
    __syncthreads();
    if (t == 0)
        slots[blockIdx.x] = wsum[0] + wsum[1] + wsum[2] + wsum[3];  // plain store
}

// ---------- kernel E: finalize (reduce 2080 slots) ----------
__global__ __launch_bounds__(256) void k_final(const double* __restrict__ slots,
                                               float* __restrict__ out) {
    __shared__ double red[256];
    int t = threadIdx.x;
    double s = 0.0;
    for (int i = t; i < NBLK; i += 256) s += slots[i];
    red[t] = s;
    __syncthreads();
    for (int off = 128; off; off >>= 1) {
        if (t < off) red[t] += red[t + off];
        __syncthreads();
    }
    if (t == 0)
        out[0] = (float)(red[0] / ((double)HALF * (double)HALF));
}

extern "C" void kernel_launch(void* const* d_in, const int* in_sizes, int n_in,
                              void* d_out, int out_size, void* d_ws, size_t ws_size,
                              hipStream_t stream) {
    const float* src = (const float*)d_in[0];
    const float* tgt = (const float*)d_in[1];
    float* out = (float*)d_out;

    double* slots     = (double*)((char*)d_ws + WS_SLOT_OFF);
    double* negg      = (double*)((char*)d_ws + WS_NEGG_OFF);
    double* sqpart    = (double*)((char*)d_ws + WS_SQPART_OFF);
    float*  cspart    = (float*)((char*)d_ws + WS_CSPART_OFF);
    float*  sq        = (float*)((char*)d_ws + WS_SQ_OFF);
    unsigned short* G = (unsigned short*)((char*)d_ws + WS_G_OFF);

    k_prep<<<PREPB, 256, 0, stream>>>(src, tgt, G, sq, cspart, sqpart);
    k_bw<<<1, 256, 0, stream>>>(cspart, sqpart, negg);
    k_mmd<<<NBLK, 256, 0, stream>>>(G, sq, negg, slots);
    k_final<<<1, 256, 0, stream>>>(slots, out);
}